// Round 17
// baseline (363.736 us; speedup 1.0000x reference)
//
#include <hip/hip_runtime.h>
#include <hip/hip_bf16.h>
#include <math.h>

#define NN_F_IN   512
#define NN_HID    256
#define NN_HEADS  8
#define NN_FH     32
#define NN_NCLASS 40
#define TAU_F     0.5f
#define LAMDA_F   0.5f
// sqrt(2 * log2(e)) : makes gram epilogue a bare exp2
#define ZN_SCALE  1.6986436f

typedef __attribute__((ext_vector_type(8))) short bf16x8;
typedef __attribute__((ext_vector_type(4))) float f32x4;

static __device__ __forceinline__ float lrelu02(float x) { return x >= 0.f ? x : 0.2f * x; }
static __device__ __forceinline__ float elu1(float x)    { return x > 0.f ? x : expm1f(x); }
static __device__ __forceinline__ float b2f(unsigned short u) {
    unsigned int x = ((unsigned int)u) << 16;
    return __uint_as_float(x);
}
static __device__ __forceinline__ unsigned short f2b(float f) {
    __hip_bfloat16 hb = __float2bfloat16(f);
    return *reinterpret_cast<unsigned short*>(&hb);
}

// ---------------------------------------------------------------------------
// Shared fc+attn body (hidden-layer geometry, ncols=256, FH=32 aligned)
// ---------------------------------------------------------------------------
static __device__ __forceinline__ void fc_attn_body(
    const unsigned short* __restrict__ A, const unsigned short* __restrict__ B,
    unsigned short* __restrict__ H, const float* __restrict__ As_,
    const float* __restrict__ Ad_, float* __restrict__ es, float* __restrict__ ed,
    int M, int K, int bx, int by) {
    const int ldH = 256;
    int t = threadIdx.x, lane = t & 63, wid = t >> 6;
    int wrow = wid >> 1, wcol = wid & 1;
    int l15 = lane & 15, lg = lane >> 4;
    int mbase = by * 64 + wrow * 32;
    int nbase = bx * 64 + wcol * 32;

    const unsigned short* Ap[2];
    const unsigned short* Bp[2];
#pragma unroll
    for (int m = 0; m < 2; ++m) {
        int rr = mbase + m * 16 + l15;
        if (rr > M - 1) rr = M - 1;
        Ap[m] = A + (size_t)rr * K + lg * 8;
        Bp[m] = B + (size_t)(nbase + m * 16 + l15) * K + lg * 8;
    }
    f32x4 acc[2][2];
#pragma unroll
    for (int m = 0; m < 2; ++m)
#pragma unroll
        for (int nn = 0; nn < 2; ++nn)
#pragma unroll
            for (int r = 0; r < 4; ++r) acc[m][nn][r] = 0.f;

    bf16x8 aP[2], bP[2], aQ[2], bQ[2];
#pragma unroll
    for (int m = 0; m < 2; ++m) {
        aP[m] = *(const bf16x8*)(Ap[m]);
        bP[m] = *(const bf16x8*)(Bp[m]);
    }
    int nhalf = K >> 6;
    int kk = 32;
    for (int it = 0; it < nhalf; ++it) {
#pragma unroll
        for (int m = 0; m < 2; ++m) {
            aQ[m] = *(const bf16x8*)(Ap[m] + kk);
            bQ[m] = *(const bf16x8*)(Bp[m] + kk);
        }
#pragma unroll
        for (int m = 0; m < 2; ++m)
#pragma unroll
            for (int nn = 0; nn < 2; ++nn)
                acc[m][nn] = __builtin_amdgcn_mfma_f32_16x16x32_bf16(aP[m], bP[nn], acc[m][nn], 0, 0, 0);
        if (it + 1 < nhalf) {
#pragma unroll
            for (int m = 0; m < 2; ++m) {
                aP[m] = *(const bf16x8*)(Ap[m] + kk + 32);
                bP[m] = *(const bf16x8*)(Bp[m] + kk + 32);
            }
        }
#pragma unroll
        for (int m = 0; m < 2; ++m)
#pragma unroll
            for (int nn = 0; nn < 2; ++nn)
                acc[m][nn] = __builtin_amdgcn_mfma_f32_16x16x32_bf16(aQ[m], bQ[nn], acc[m][nn], 0, 0, 0);
        kk += 64;
    }
#pragma unroll
    for (int m = 0; m < 2; ++m) {
#pragma unroll
        for (int nn = 0; nn < 2; ++nn) {
            int col = nbase + nn * 16 + l15;
#pragma unroll
            for (int r = 0; r < 4; ++r) {
                int row = mbase + m * 16 + lg * 4 + r;
                if (row < M) H[(size_t)row * ldH + col] = f2b(acc[m][nn][r]);
            }
        }
    }
    int hh = bx * 2 + wcol;
    float a0 = As_[hh * 32 + l15], a1 = As_[hh * 32 + 16 + l15];
    float d0 = Ad_[hh * 32 + l15], d1 = Ad_[hh * 32 + 16 + l15];
#pragma unroll
    for (int m = 0; m < 2; ++m) {
#pragma unroll
        for (int r = 0; r < 4; ++r) {
            float ps = acc[m][0][r] * a0 + acc[m][1][r] * a1;
            float pd = acc[m][0][r] * d0 + acc[m][1][r] * d1;
            ps += __shfl_xor(ps, 1, 64); pd += __shfl_xor(pd, 1, 64);
            ps += __shfl_xor(ps, 2, 64); pd += __shfl_xor(pd, 2, 64);
            ps += __shfl_xor(ps, 4, 64); pd += __shfl_xor(pd, 4, 64);
            ps += __shfl_xor(ps, 8, 64); pd += __shfl_xor(pd, 8, 64);
            if (l15 == 0) {
                int row = mbase + m * 16 + lg * 4 + r;
                if (row < M) {
                    es[row * NN_HEADS + hh] = ps;
                    ed[row * NN_HEADS + hh] = pd;
                }
            }
        }
    }
}

// ---------------------------------------------------------------------------
// FAT front: X cast + 4 W casts + edge count, one launch.
// ---------------------------------------------------------------------------
__global__ void prep_count_kernel(const float* __restrict__ x,
                                  const float* __restrict__ W0, const float* __restrict__ W1,
                                  const float* __restrict__ W2, const float* __restrict__ Wo,
                                  unsigned short* __restrict__ Xb,
                                  unsigned short* __restrict__ Wt0, unsigned short* __restrict__ Wt1,
                                  unsigned short* __restrict__ Wt2, unsigned short* __restrict__ Wto,
                                  int n4X,
                                  const int* __restrict__ dst, int* __restrict__ counts,
                                  int E, int nCountB) {
    if (blockIdx.x < nCountB) {
        int e = blockIdx.x * 256 + threadIdx.x;
        if (e < E) atomicAdd(&counts[dst[e]], 1);
        return;
    }
    int i = (blockIdx.x - nCountB) * 256 + threadIdx.x;
    if (i < n4X) {
        float4 v = *(const float4*)(x + (size_t)i * 4);
        ushort4 o;
        o.x = f2b(v.x); o.y = f2b(v.y); o.z = f2b(v.z); o.w = f2b(v.w);
        *(ushort4*)(Xb + (size_t)i * 4) = o;
        return;
    }
    i -= n4X;
    if (i < 256 * 512) {
        int np = i >> 9, k = i & 511;
        Wt0[i] = f2b(W0[(size_t)k * 256 + np]);
        return;
    }
    i -= 256 * 512;
    if (i < 256 * 256) {
        int np = i >> 8, k = i & 255;
        Wt1[i] = f2b(W1[(size_t)k * 256 + np]);
        return;
    }
    i -= 256 * 256;
    if (i < 256 * 256) {
        int np = i >> 8, k = i & 255;
        Wt2[i] = f2b(W2[(size_t)k * 256 + np]);
        return;
    }
    i -= 256 * 256;
    if (i < 384 * 256) {
        int np = i >> 8, k = i & 255;
        Wto[i] = f2b(np < 320 ? Wo[(size_t)k * 320 + np] : 0.f);
    }
}

// ---------------------------------------------------------------------------
// CSR scan
// ---------------------------------------------------------------------------
__global__ void scan_kernel(const int* __restrict__ counts, int* __restrict__ row_start,
                            int* __restrict__ cursor, int n) {
    __shared__ int s[1024];
    int t  = threadIdx.x;
    int ch = (n + 1023) / 1024;
    int lo = t * ch;
    int sum = 0;
    for (int j = 0; j < ch; ++j) {
        int i = lo + j;
        if (i < n) sum += counts[i];
    }
    s[t] = sum;
    __syncthreads();
    for (int off = 1; off < 1024; off <<= 1) {
        int v = 0;
        if (t >= off) v = s[t - off];
        __syncthreads();
        s[t] += v;
        __syncthreads();
    }
    int run = (t == 0) ? 0 : s[t - 1];
    for (int j = 0; j < ch; ++j) {
        int i = lo + j;
        if (i < n) {
            row_start[i] = run;
            cursor[i] = run;
            run += counts[i];
        }
    }
    if (t == 1023) row_start[n] = s[1023];
}

// ---------------------------------------------------------------------------
// FAT: CSR scatter (blocks [0,nSc)) + layer-0 fc_attn (rest). Independent:
// scatter needs cursor (scan); fc needs Xb/Wt0 (prep). Overlaps scatter's
// random atomics under fc's MFMA phase.
// ---------------------------------------------------------------------------
__global__ __launch_bounds__(256) void scatter_fc0_kernel(
    const int* __restrict__ src, const int* __restrict__ dst,
    int* __restrict__ cursor, int* __restrict__ csr_src, int E, int nSc,
    const unsigned short* __restrict__ A, const unsigned short* __restrict__ B,
    unsigned short* __restrict__ H, const float* __restrict__ As_,
    const float* __restrict__ Ad_, float* __restrict__ es, float* __restrict__ ed,
    int M, int K) {
    if (blockIdx.x < nSc) {
        int e = blockIdx.x * 256 + threadIdx.x;
        if (e < E) {
            int d   = dst[e];
            int pos = atomicAdd(&cursor[d], 1);
            csr_src[pos] = src[e];
        }
        return;
    }
    int idx = blockIdx.x - nSc;
    fc_attn_body(A, B, H, As_, Ad_, es, ed, M, K, idx & 3, idx >> 2);
}

// ---------------------------------------------------------------------------
// Standalone fc_attn (layers 1,2)
// ---------------------------------------------------------------------------
__global__ __launch_bounds__(256) void fc_attn_mfma(
    const unsigned short* __restrict__ A, const unsigned short* __restrict__ B,
    unsigned short* __restrict__ H, const float* __restrict__ As_,
    const float* __restrict__ Ad_, float* __restrict__ es, float* __restrict__ ed,
    int M, int K) {
    fc_attn_body(A, B, H, As_, Ad_, es, ed, M, K, blockIdx.x, blockIdx.y);
}

// ---------------------------------------------------------------------------
// Hidden-layer gather, FUSED edge weights + optional rownorm; 8-deep MLP.
// ---------------------------------------------------------------------------
__global__ __launch_bounds__(256) void gather_hidden(
    const unsigned short* __restrict__ Hm, const float* __restrict__ es,
    const float* __restrict__ ed, const int* __restrict__ csr_src,
    const int* __restrict__ row_start, const unsigned short* __restrict__ last,
    unsigned short* __restrict__ out, int n, float beta,
    unsigned short* __restrict__ znb, float* __restrict__ dvec) {
    int lane = threadIdx.x & 63;
    int nn   = blockIdx.x * 4 + (threadIdx.x >> 6);
    if (nn >= n) return;
    int s0 = row_start[nn], s1 = row_start[nn + 1];
    int h2 = lane >> 3;
    float edh = ed[nn * NN_HEADS + h2];

    float zacc = 0.f;
    float a0 = 0.f, a1 = 0.f, a2 = 0.f, a3 = 0.f;
    int fullEnd = s0 + ((s1 - s0) & ~7);
    int e = s0;
    for (; e < fullEnd; e += 8) {
        int idx[8];
        float q[8];
#pragma unroll
        for (int j = 0; j < 8; ++j) idx[j] = csr_src[e + j];
#pragma unroll
        for (int j = 0; j < 8; ++j) q[j] = es[idx[j] * NN_HEADS + h2];
        ushort4 r[8];
#pragma unroll
        for (int j = 0; j < 8; ++j) r[j] = *(const ushort4*)&Hm[(size_t)idx[j] * NN_HID + lane * 4];
#pragma unroll
        for (int j = 0; j < 8; ++j) {
            float w = __expf(lrelu02(q[j] + edh));
            zacc += w;
            a0 += w * b2f(r[j].x); a1 += w * b2f(r[j].y);
            a2 += w * b2f(r[j].z); a3 += w * b2f(r[j].w);
        }
    }
    if (e < s1) {
        int c = s1 - e;
        int idx[8];
        float q[8];
#pragma unroll
        for (int j = 0; j < 8; ++j) idx[j] = csr_src[(j < c) ? e + j : e];
#pragma unroll
        for (int j = 0; j < 8; ++j) q[j] = es[idx[j] * NN_HEADS + h2];
        ushort4 r[8];
#pragma unroll
        for (int j = 0; j < 8; ++j) r[j] = *(const ushort4*)&Hm[(size_t)idx[j] * NN_HID + lane * 4];
#pragma unroll
        for (int j = 0; j < 8; ++j) {
            if (j < c) {
                float w = __expf(lrelu02(q[j] + edh));
                zacc += w;
                a0 += w * b2f(r[j].x); a1 += w * b2f(r[j].y);
                a2 += w * b2f(r[j].z); a3 += w * b2f(r[j].w);
            }
        }
    }
    float zi = 1.f / zacc;
    float v0 = elu1(a0 * zi), v1 = elu1(a1 * zi), v2 = elu1(a2 * zi), v3 = elu1(a3 * zi);
    if (beta >= 0.f) {
        ushort4 lv = *(const ushort4*)&last[(size_t)nn * NN_HID + lane * 4];
        v0 = beta * b2f(lv.x) + (1.f - beta) * v0;
        v1 = beta * b2f(lv.y) + (1.f - beta) * v1;
        v2 = beta * b2f(lv.z) + (1.f - beta) * v2;
        v3 = beta * b2f(lv.w) + (1.f - beta) * v3;
    }
    ushort4 o;
    o.x = f2b(v0); o.y = f2b(v1); o.z = f2b(v2); o.w = f2b(v3);
    *(ushort4*)&out[(size_t)nn * NN_HID + lane * 4] = o;

    if (znb) {
        float ss = v0 * v0 + v1 * v1 + v2 * v2 + v3 * v3;
        ss += __shfl_xor(ss, 1, 64);
        ss += __shfl_xor(ss, 2, 64);
        ss += __shfl_xor(ss, 4, 64);
        ss += __shfl_xor(ss, 8, 64);
        ss += __shfl_xor(ss, 16, 64);
        ss += __shfl_xor(ss, 32, 64);
        float m = fmaxf(sqrtf(ss), 1e-12f);
        float sc = ZN_SCALE / m;
        ushort4 zo;
        zo.x = f2b(v0 * sc); zo.y = f2b(v1 * sc);
        zo.z = f2b(v2 * sc); zo.w = f2b(v3 * sc);
        *(ushort4*)&znb[(size_t)nn * NN_HID + lane * 4] = zo;
        if (lane == 0) dvec[nn] = __expf((ss / (m * m)) * (1.f / TAU_F));
    }
}

// ---------------------------------------------------------------------------
// FAT KERNEL: output-layer fc (blocks [0,nfc)) + symmetric gram (rest).
// ---------------------------------------------------------------------------
__global__ __launch_bounds__(256) void gram_fc_mfma(
    const short* __restrict__ znb, float* __restrict__ P2d, int n,
    int T, int nwg, int Npad,
    const unsigned short* __restrict__ A, const unsigned short* __restrict__ Bw,
    unsigned short* __restrict__ H, int M, int nfc, int fcX) {
    __shared__ short As[2][128 * 64];
    __shared__ short Bs[2][128 * 64];

    int t    = threadIdx.x;
    int lane = t & 63;
    int wid  = t >> 6;
    int l15  = lane & 15, lg = lane >> 4;

    if (blockIdx.x < nfc) {
        const int K = 256, ncols = 320, ldH = 320;
        int idx = blockIdx.x;
        int bx = idx % fcX, by = idx / fcX;
        int wrow = wid >> 1, wcol = wid & 1;
        int mbase = by * 64 + wrow * 32;
        int nbase = bx * 64 + wcol * 32;

        const unsigned short* Ap[2];
        const unsigned short* Bp[2];
#pragma unroll
        for (int m = 0; m < 2; ++m) {
            int rr = mbase + m * 16 + l15;
            if (rr > M - 1) rr = M - 1;
            Ap[m] = A + (size_t)rr * K + lg * 8;
            Bp[m] = Bw + (size_t)(nbase + m * 16 + l15) * K + lg * 8;
        }
        f32x4 acc[2][2];
#pragma unroll
        for (int m = 0; m < 2; ++m)
#pragma unroll
            for (int nn = 0; nn < 2; ++nn)
#pragma unroll
                for (int r = 0; r < 4; ++r) acc[m][nn][r] = 0.f;

        bf16x8 aP[2], bP[2], aQ[2], bQ[2];
#pragma unroll
        for (int m = 0; m < 2; ++m) {
            aP[m] = *(const bf16x8*)(Ap[m]);
            bP[m] = *(const bf16x8*)(Bp[m]);
        }
        int kk = 32;
#pragma unroll
        for (int it = 0; it < 4; ++it) {
#pragma unroll
            for (int m = 0; m < 2; ++m) {
                aQ[m] = *(const bf16x8*)(Ap[m] + kk);
                bQ[m] = *(const bf16x8*)(Bp[m] + kk);
            }
#pragma unroll
            for (int m = 0; m < 2; ++m)
#pragma unroll
                for (int nn = 0; nn < 2; ++nn)
                    acc[m][nn] = __builtin_amdgcn_mfma_f32_16x16x32_bf16(aP[m], bP[nn], acc[m][nn], 0, 0, 0);
            if (it < 3) {
#pragma unroll
                for (int m = 0; m < 2; ++m) {
                    aP[m] = *(const bf16x8*)(Ap[m] + kk + 32);
                    bP[m] = *(const bf16x8*)(Bp[m] + kk + 32);
                }
            }
#pragma unroll
            for (int m = 0; m < 2; ++m)
#pragma unroll
                for (int nn = 0; nn < 2; ++nn)
                    acc[m][nn] = __builtin_amdgcn_mfma_f32_16x16x32_bf16(aQ[m], bQ[nn], acc[m][nn], 0, 0, 0);
            kk += 64;
        }
#pragma unroll
        for (int m = 0; m < 2; ++m) {
#pragma unroll
            for (int nn = 0; nn < 2; ++nn) {
                int col = nbase + nn * 16 + l15;
                if (col >= ncols) continue;
#pragma unroll
                for (int r = 0; r < 4; ++r) {
                    int row = mbase + m * 16 + lg * 4 + r;
                    if (row < M) H[(size_t)row * ldH + col] = f2b(acc[m][nn][r]);
                }
            }
        }
        return;
    }

    // gram path
    int b = blockIdx.x - nfc;
    int q = nwg >> 3, r8 = nwg & 7, xc = b & 7, oo = b >> 3;
    int sid = (xc < r8 ? xc * (q + 1) : r8 * (q + 1) + (xc - r8) * q) + oo;
    int bi = 0, rem = sid;
    while (rem >= T - bi) { rem -= T - bi; ++bi; }
    int bj = bi + rem;
    int i0 = bi * 128, j0 = bj * 128;

    int wrow = wid >> 1, wcol = wid & 1;
    int srow = lane >> 3;
    int sch  = lane & 7;

    f32x4 acc[4][4];
#pragma unroll
    for (int m = 0; m < 4; ++m)
#pragma unroll
        for (int nn = 0; nn < 4; ++nn)
#pragma unroll
            for (int r = 0; r < 4; ++r) acc[m][nn][r] = 0.f;

    bf16x8 sa[2][4], sb[2][4];
#pragma unroll
    for (int sl = 0; sl < 2; ++sl)
#pragma unroll
        for (int s = 0; s < 4; ++s) {
            int row = wid * 32 + s * 8 + srow;
            int gch = sch ^ (row & 7);
            sa[sl][s] = *(const bf16x8*)(znb + (size_t)(i0 + row) * NN_HID + sl * 64 + gch * 8);
            sb[sl][s] = *(const bf16x8*)(znb + (size_t)(j0 + row) * NN_HID + sl * 64 + gch * 8);
        }

#pragma unroll
    for (int kt = 0; kt < 2; ++kt) {
#pragma unroll
        for (int sl = 0; sl < 2; ++sl)
#pragma unroll
            for (int s = 0; s < 4; ++s) {
                int row = wid * 32 + s * 8 + srow;
                *(bf16x8*)(&As[sl][row * 64 + sch * 8]) = sa[sl][s];
                *(bf16x8*)(&Bs[sl][row * 64 + sch * 8]) = sb[sl][s];
            }
        __syncthreads();
        if (kt == 0) {
#pragma unroll
            for (int sl = 0; sl < 2; ++sl)
#pragma unroll
                for (int s = 0; s < 4; ++s) {
                    int row = wid * 32 + s * 8 + srow;
                    int gch = sch ^ (row & 7);
                    sa[sl][s] = *(const bf16x8*)(znb + (size_t)(i0 + row) * NN_HID + 128 + sl * 64 + gch * 8);
                    sb[sl][s] = *(const bf16x8*)(znb + (size_t)(j0 + row) * NN_HID + 128 + sl * 64 + gch * 8);
                }
        }
#pragma unroll
        for (int sl = 0; sl < 2; ++sl) {
#pragma unroll
            for (int ks = 0; ks < 2; ++ks) {
                bf16x8 av[4], bv[4];
#pragma unroll
                for (int m = 0; m < 4; ++m) {
                    int Ra = wrow * 64 + m * 16 + l15;
                    int Rb = wcol * 64 + m * 16 + l15;
                    int ca = (ks * 4 + lg) ^ (Ra & 7);
                    int cb = (ks * 4 + lg) ^ (Rb & 7);
                    av[m] = *(const bf16x8*)(&As[sl][Ra * 64 + ca * 8]);
                    bv[m] = *(const bf16x8*)(&Bs[sl][Rb * 64 + cb * 8]);
                }
#pragma unroll
                for (int m = 0; m < 4; ++m)
#pragma unroll
                    for (int nn = 0; nn < 4; ++nn)
                        acc[m][nn] = __builtin_amdgcn_mfma_f32_16x16x32_bf16(av[m], bv[nn], acc[m][nn], 0, 0, 0);
            }
        }
        if (kt == 0) __syncthreads();
    }

    int i0w = i0 + wrow * 64;
    int j0w = j0 + wcol * 64;
    bool diag = (bj == bi);
    if (bj == T - 1) {
#pragma unroll
        for (int m = 0; m < 4; ++m)
#pragma unroll
            for (int nn = 0; nn < 4; ++nn) {
                int gj = j0w + nn * 16 + l15;
                bool jok = gj < n;
#pragma unroll
                for (int r = 0; r < 4; ++r) {
                    int gi = i0w + m * 16 + lg * 4 + r;
                    acc[m][nn][r] = (jok && gi < n) ? __builtin_exp2f(acc[m][nn][r]) : 0.f;
                }
            }
    } else {
#pragma unroll
        for (int m = 0; m < 4; ++m)
#pragma unroll
            for (int nn = 0; nn < 4; ++nn)
#pragma unroll
                for (int r = 0; r < 4; ++r)
                    acc[m][nn][r] = __builtin_exp2f(acc[m][nn][r]);
    }
    float* rowslot = P2d + (size_t)(2 * bj + wcol) * Npad;
#pragma unroll
    for (int m = 0; m < 4; ++m) {
#pragma unroll
        for (int r = 0; r < 4; ++r) {
            float v = acc[m][0][r] + acc[m][1][r] + acc[m][2][r] + acc[m][3][r];
            v += __shfl_xor(v, 1, 64);
            v += __shfl_xor(v, 2, 64);
            v += __shfl_xor(v, 4, 64);
            v += __shfl_xor(v, 8, 64);
            if (l15 == 0) {
                int gi = i0w + m * 16 + lg * 4 + r;
                if (gi < n) rowslot[gi] = v;
            }
        }
    }
    if (!diag) {
        float* colslot = P2d + (size_t)(2 * bi + wrow) * Npad;
#pragma unroll
        for (int nn = 0; nn < 4; ++nn) {
            float v = 0.f;
#pragma unroll
            for (int m = 0; m < 4; ++m)
#pragma unroll
                for (int r = 0; r < 4; ++r) v += acc[m][nn][r];
            v += __shfl_xor(v, 16, 64);
            v += __shfl_xor(v, 32, 64);
            if (lg == 0) {
                int gj = j0w + nn * 16 + l15;
                if (gj < n) colslot[gj] = v;
            }
        }
    }
}

// ---------------------------------------------------------------------------
// FAT: final-layer attn dots (blocks [0,nAt)) + fold (rest). Independent.
// ---------------------------------------------------------------------------
__global__ __launch_bounds__(256) void attn_fold_kernel(
    const unsigned short* __restrict__ Hm, const float* __restrict__ As,
    const float* __restrict__ Ad, float* __restrict__ es, float* __restrict__ ed,
    int n, int df, int nAt,
    const float* __restrict__ P2d, float* __restrict__ R, int slots, int Npad) {
    if (blockIdx.x < nAt) {
        int idx = blockIdx.x * 256 + threadIdx.x;
        if (idx >= n * NN_HEADS) return;
        int nn = idx / NN_HEADS, hh = idx - nn * NN_HEADS;
        const unsigned short* hp = Hm + (size_t)nn * NN_HEADS * df + hh * df;
        const float* ap = As + hh * df;
        const float* bp = Ad + hh * df;
        float s1 = 0.f, s2 = 0.f;
        for (int d = 0; d < df; d += 4) {
            ushort4 hv = *(const ushort4*)(hp + d);
            float4 av = *(const float4*)(ap + d);
            float4 bv = *(const float4*)(bp + d);
            float h0 = b2f(hv.x), h1 = b2f(hv.y), h2 = b2f(hv.z), h3 = b2f(hv.w);
            s1 += h0 * av.x + h1 * av.y + h2 * av.z + h3 * av.w;
            s2 += h0 * bv.x + h1 * bv.y + h2 * bv.z + h3 * bv.w;
        }
        es[idx] = s1;
        ed[idx] = s2;
        return;
    }
    int i = (blockIdx.x - nAt) * 256 + threadIdx.x;
    if (i >= n) return;
    const float* p = P2d + i;
    float s0 = 0.f, s1 = 0.f, s2 = 0.f, s3 = 0.f;
    int sl = 0;
    for (; sl + 4 <= slots; sl += 4) {
        s0 += p[(size_t)(sl + 0) * Npad];
        s1 += p[(size_t)(sl + 1) * Npad];
        s2 += p[(size_t)(sl + 2) * Npad];
        s3 += p[(size_t)(sl + 3) * Npad];
    }
    for (; sl < slots; ++sl) s0 += p[(size_t)sl * Npad];
    R[i] = (s0 + s1) + (s2 + s3);
}

// ---------------------------------------------------------------------------
// FAT: final gather with INLINE edge weights (no wC/zinv round trip) +
// head-mean + log_softmax  (blocks [0,n)) ; loss reduction (block n).
// ---------------------------------------------------------------------------
__global__ void gather_final_loss(
    const unsigned short* __restrict__ Hm, const float* __restrict__ es,
    const float* __restrict__ ed, const int* __restrict__ csr_src,
    const int* __restrict__ row_start, float* __restrict__ dout, int n,
    const float* __restrict__ R, const float* __restrict__ dvec,
    float* __restrict__ out_loss) {
    int t = threadIdx.x;  // 0..319
    if ((int)blockIdx.x >= n) {
        // loss block
        __shared__ float s[320];
        float sum = 0.f;
        for (int i = t; i < n; i += 320) {
            float d   = dvec[i];
            float off = R[i] - d;
            sum += -logf(d / (off + off));
        }
        s[t] = sum;
        __syncthreads();
        if (t < 64) s[t] += s[t + 256];
        __syncthreads();
        for (int o = 128; o > 0; o >>= 1) {
            if (t < o) s[t] += s[t + o];
            __syncthreads();
        }
        if (t == 0) *out_loss = s[0] / n;
        return;
    }
    int nn = blockIdx.x;
    __shared__ float accs[NN_HEADS * NN_NCLASS];
    int s0 = row_start[nn], s1 = row_start[nn + 1];
    int hh = t / NN_NCLASS;
    float edh = ed[nn * NN_HEADS + hh];
    float acc = 0.f, zacc = 0.f;
    const int LD = NN_HEADS * NN_NCLASS;
    int fullEnd = s0 + ((s1 - s0) & ~7);
    int e = s0;
    for (; e < fullEnd; e += 8) {
        int idx[8];
        float q[8];
#pragma unroll
        for (int j = 0; j < 8; ++j) idx[j] = csr_src[e + j];
#pragma unroll
        for (int j = 0; j < 8; ++j) q[j] = es[idx[j] * NN_HEADS + hh];
        float v[8];
#pragma unroll
        for (int j = 0; j < 8; ++j) v[j] = b2f(Hm[(size_t)idx[j] * LD + t]);
#pragma unroll
        for (int j = 0; j < 8; ++j) {
            float w = __expf(lrelu02(q[j] + edh));
            zacc += w;
            acc += w * v[j];
        }
    }
    if (e < s1) {
        int c = s1 - e;
        int idx[8];
        float q[8];
#pragma unroll
        for (int j = 0; j < 8; ++j) idx[j] = csr_src[(j < c) ? e + j : e];
#pragma unroll
        for (int j = 0; j < 8; ++j) q[j] = es[idx[j] * NN_HEADS + hh];
        float v[8];
#pragma unroll
        for (int j = 0; j < 8; ++j) v[j] = b2f(Hm[(size_t)idx[j] * LD + t]);
#pragma unroll
        for (int j = 0; j < 8; ++j) {
            if (j < c) {
                float w = __expf(lrelu02(q[j] + edh));
                zacc += w;
                acc += w * v[j];
            }
        }
    }
    accs[t] = acc / zacc;
    __syncthreads();
    if (t < 64) {
        float v = -INFINITY;
        if (t < NN_NCLASS) {
            float sacc = 0.f;
#pragma unroll
            for (int h2 = 0; h2 < NN_HEADS; ++h2) sacc += accs[h2 * NN_NCLASS + t];
            v = sacc * (1.f / NN_HEADS);
        }
        float mx = v;
#pragma unroll
        for (int o = 1; o < 64; o <<= 1) mx = fmaxf(mx, __shfl_xor(mx, o, 64));
        float ex = (t < NN_NCLASS) ? expf(v - mx) : 0.f;
        float se = ex;
#pragma unroll
        for (int o = 1; o < 64; o <<= 1) se += __shfl_xor(se, o, 64);
        if (t < NN_NCLASS) dout[(size_t)nn * NN_NCLASS + t] = (v - mx) - logf(se);
    }
}

// ---------------------------------------------------------------------------
extern "C" void kernel_launch(void* const* d_in, const int* in_sizes, int n_in,
                              void* d_out, int out_size, void* d_ws, size_t ws_size,
                              hipStream_t stream) {
    const float* x   = (const float*)d_in[0];
    const int*   src = (const int*)d_in[1];
    const int*   dst = (const int*)d_in[2];
    const float* W0  = (const float*)d_in[3];
    const float* a0s = (const float*)d_in[4];
    const float* a0d = (const float*)d_in[5];
    const float* W1  = (const float*)d_in[6];
    const float* a1s = (const float*)d_in[7];
    const float* a1d = (const float*)d_in[8];
    const float* W2  = (const float*)d_in[9];
    const float* a2s = (const float*)d_in[10];
    const float* a2d = (const float*)d_in[11];
    const float* Wout= (const float*)d_in[12];
    const float* aos = (const float*)d_in[13];
    const float* aod = (const float*)d_in[14];

    int N = in_sizes[0] / NN_F_IN;
    int E = in_sizes[1];
    int Npad = ((N + 127) / 128) * 128;
    int T = Npad / 128;
    int nwg = T * (T + 1) / 2;
    float* out = (float*)d_out;

    char*  ws  = (char*)d_ws;
    size_t off = 0;
    auto alloc = [&](size_t bytes) -> void* {
        void* p = ws + off;
        off += bytes;
        off = (off + 255) & ~(size_t)255;
        return p;
    };
    unsigned short* Hb = (unsigned short*)alloc((size_t)N * 320 * 2);
    unsigned short* znb = (unsigned short*)alloc((size_t)Npad * NN_HID * 2);
    unsigned short* Bl = (unsigned short*)alloc((size_t)N * NN_HID * 2);
    unsigned short* Bc = (unsigned short*)alloc((size_t)N * NN_HID * 2);
    size_t xbBytes = (size_t)N * NN_F_IN * 2;
    size_t p2Bytes = (size_t)2 * T * Npad * 4;
    void* XbP2d = alloc(xbBytes > p2Bytes ? xbBytes : p2Bytes);
    unsigned short* Xb  = (unsigned short*)XbP2d;
    float*          P2d = (float*)XbP2d;
    unsigned short* Wt0 = (unsigned short*)alloc((size_t)256 * 512 * 2);
    unsigned short* Wt1 = (unsigned short*)alloc((size_t)256 * 256 * 2);
    unsigned short* Wt2 = (unsigned short*)alloc((size_t)256 * 256 * 2);
    unsigned short* Wto = (unsigned short*)alloc((size_t)384 * 256 * 2);
    float* es     = (float*)alloc((size_t)N * NN_HEADS * 4);
    float* ed     = (float*)alloc((size_t)N * NN_HEADS * 4);
    float* Rrow   = (float*)alloc((size_t)N * 4);
    float* dvec   = (float*)alloc((size_t)N * 4);
    int*   counts = (int*)alloc((size_t)N * 4);
    int*   rs     = (int*)alloc((size_t)(N + 1) * 4);
    int*   cursor = (int*)alloc((size_t)N * 4);
    int*   csr    = (int*)alloc((size_t)E * 4);

    // ---- memsets (counts + znb pad rows)
    hipMemsetAsync(counts, 0, (size_t)N * 4, stream);
    if (Npad > N)
        hipMemsetAsync(znb + (size_t)N * NN_HID, 0, (size_t)(Npad - N) * NN_HID * 2, stream);

    // ---- FAT front: count + prep
    int n4X = N * NN_F_IN / 4;
    int prepTotal = n4X + 256 * 512 + 256 * 256 + 256 * 256 + 384 * 256;
    int nCountB = (E + 255) / 256;
    int nPrepB  = (prepTotal + 255) / 256;
    prep_count_kernel<<<nCountB + nPrepB, 256, 0, stream>>>(
        x, W0, W1, W2, Wout, Xb, Wt0, Wt1, Wt2, Wto, n4X, dst, counts, E, nCountB);
    scan_kernel<<<1, 1024, 0, stream>>>(counts, rs, cursor, N);

    int atGrid = (N * NN_HEADS + 255) / 256;
    int ghGrid = (N + 3) / 4;
    int mT64 = (N + 63) / 64;

    // ---- FAT: scatter + layer-0 fc_attn (independent)
    int nSc = (E + 255) / 256;
    scatter_fc0_kernel<<<nSc + 4 * mT64, 256, 0, stream>>>(
        src, dst, cursor, csr, E, nSc,
        Xb, Wt0, Hb, a0s, a0d, es, ed, N, 512);
    gather_hidden<<<ghGrid, 256, 0, stream>>>(Hb, es, ed, csr, rs, nullptr, Bl, N, -1.f,
                                              nullptr, nullptr);

    // ---- layer 1
    fc_attn_mfma<<<dim3(4, mT64), 256, 0, stream>>>(Bl, Wt1, Hb, a1s, a1d, es, ed, N, 256);
    gather_hidden<<<ghGrid, 256, 0, stream>>>(Hb, es, ed, csr, rs, Bl, Bc, N, LAMDA_F / 3.f,
                                              nullptr, nullptr);

    // ---- layer 2 (+ fused rownorm)
    fc_attn_mfma<<<dim3(4, mT64), 256, 0, stream>>>(Bc, Wt2, Hb, a2s, a2d, es, ed, N, 256);
    gather_hidden<<<ghGrid, 256, 0, stream>>>(Hb, es, ed, csr, rs, Bc, Bl, N, LAMDA_F / 4.f,
                                              znb, dvec);

    // ---- FAT: output-layer fc + gram
    int fcX = 5;
    int nfc = fcX * mT64;
    gram_fc_mfma<<<nfc + nwg, 256, 0, stream>>>((const short*)znb, P2d, N, T, nwg, Npad,
                                                Bl, Wto, Hb, N, nfc, fcX);

    // ---- FAT: attn(final) + fold
    int foldB = (N + 255) / 256;
    attn_fold_kernel<<<atGrid + foldB, 256, 0, stream>>>(
        Hb, aos, aod, es, ed, N, NN_NCLASS, atGrid, P2d, Rrow, 2 * T, Npad);

    // ---- FAT: final gather (inline edge weights) + loss
    gather_final_loss<<<N + 1, NN_HEADS * NN_NCLASS, 0, stream>>>(
        Hb, es, ed, csr, rs, out, N, Rrow, dvec, out + (size_t)N * NN_NCLASS);
}

// Round 18
// 351.300 us; speedup vs baseline: 1.0354x; 1.0354x over previous
//
#include <hip/hip_runtime.h>
#include <hip/hip_bf16.h>
#include <math.h>

#define NN_F_IN   512
#define NN_HID    256
#define NN_HEADS  8
#define NN_FH     32
#define NN_NCLASS 40
#define TAU_F     0.5f
#define LAMDA_F   0.5f
// sqrt(2 * log2(e)) : makes gram epilogue a bare exp2
#define ZN_SCALE  1.6986436f

typedef __attribute__((ext_vector_type(8))) short bf16x8;
typedef __attribute__((ext_vector_type(4))) float f32x4;

static __device__ __forceinline__ float lrelu02(float x) { return x >= 0.f ? x : 0.2f * x; }
static __device__ __forceinline__ float elu1(float x)    { return x > 0.f ? x : expm1f(x); }
static __device__ __forceinline__ float b2f(unsigned short u) {
    unsigned int x = ((unsigned int)u) << 16;
    return __uint_as_float(x);
}
static __device__ __forceinline__ unsigned short f2b(float f) {
    __hip_bfloat16 hb = __float2bfloat16(f);
    return *reinterpret_cast<unsigned short*>(&hb);
}

// ---------------------------------------------------------------------------
// FAT front: X cast + 4 W casts + edge count, one launch (independent parts).
// ---------------------------------------------------------------------------
__global__ void prep_count_kernel(const float* __restrict__ x,
                                  const float* __restrict__ W0, const float* __restrict__ W1,
                                  const float* __restrict__ W2, const float* __restrict__ Wo,
                                  unsigned short* __restrict__ Xb,
                                  unsigned short* __restrict__ Wt0, unsigned short* __restrict__ Wt1,
                                  unsigned short* __restrict__ Wt2, unsigned short* __restrict__ Wto,
                                  int n4X,
                                  const int* __restrict__ dst, int* __restrict__ counts,
                                  int E, int nCountB) {
    if (blockIdx.x < nCountB) {
        int e = blockIdx.x * 256 + threadIdx.x;
        if (e < E) atomicAdd(&counts[dst[e]], 1);
        return;
    }
    int i = (blockIdx.x - nCountB) * 256 + threadIdx.x;
    if (i < n4X) {
        float4 v = *(const float4*)(x + (size_t)i * 4);
        ushort4 o;
        o.x = f2b(v.x); o.y = f2b(v.y); o.z = f2b(v.z); o.w = f2b(v.w);
        *(ushort4*)(Xb + (size_t)i * 4) = o;
        return;
    }
    i -= n4X;
    if (i < 256 * 512) {            // Wt0: Np=256, K=512, Nc=256
        int np = i >> 9, k = i & 511;
        Wt0[i] = f2b(W0[(size_t)k * 256 + np]);
        return;
    }
    i -= 256 * 512;
    if (i < 256 * 256) {            // Wt1
        int np = i >> 8, k = i & 255;
        Wt1[i] = f2b(W1[(size_t)k * 256 + np]);
        return;
    }
    i -= 256 * 256;
    if (i < 256 * 256) {            // Wt2
        int np = i >> 8, k = i & 255;
        Wt2[i] = f2b(W2[(size_t)k * 256 + np]);
        return;
    }
    i -= 256 * 256;
    if (i < 384 * 256) {            // Wto: Np=384, K=256, Nc=320
        int np = i >> 8, k = i & 255;
        Wto[i] = f2b(np < 320 ? Wo[(size_t)k * 320 + np] : 0.f);
    }
}

// ---------------------------------------------------------------------------
// MFMA GEMM + FUSED attention dots (hidden layers, ncols=256, FH=32).
// ---------------------------------------------------------------------------
__global__ __launch_bounds__(256) void fc_attn_mfma(
    const unsigned short* __restrict__ A, const unsigned short* __restrict__ B,
    unsigned short* __restrict__ H, const float* __restrict__ As_,
    const float* __restrict__ Ad_, float* __restrict__ es, float* __restrict__ ed,
    int M, int K) {
    const int ldH = 256;
    int t = threadIdx.x, lane = t & 63, wid = t >> 6;
    int wrow = wid >> 1, wcol = wid & 1;
    int l15 = lane & 15, lg = lane >> 4;
    int mbase = blockIdx.y * 64 + wrow * 32;
    int nbase = blockIdx.x * 64 + wcol * 32;

    const unsigned short* Ap[2];
    const unsigned short* Bp[2];
#pragma unroll
    for (int m = 0; m < 2; ++m) {
        int rr = mbase + m * 16 + l15;
        if (rr > M - 1) rr = M - 1;
        Ap[m] = A + (size_t)rr * K + lg * 8;
        Bp[m] = B + (size_t)(nbase + m * 16 + l15) * K + lg * 8;
    }
    f32x4 acc[2][2];
#pragma unroll
    for (int m = 0; m < 2; ++m)
#pragma unroll
        for (int nn = 0; nn < 2; ++nn)
#pragma unroll
            for (int r = 0; r < 4; ++r) acc[m][nn][r] = 0.f;

    bf16x8 aP[2], bP[2], aQ[2], bQ[2];
#pragma unroll
    for (int m = 0; m < 2; ++m) {
        aP[m] = *(const bf16x8*)(Ap[m]);
        bP[m] = *(const bf16x8*)(Bp[m]);
    }
    int nhalf = K >> 6;
    int kk = 32;
    for (int it = 0; it < nhalf; ++it) {
#pragma unroll
        for (int m = 0; m < 2; ++m) {
            aQ[m] = *(const bf16x8*)(Ap[m] + kk);
            bQ[m] = *(const bf16x8*)(Bp[m] + kk);
        }
#pragma unroll
        for (int m = 0; m < 2; ++m)
#pragma unroll
            for (int nn = 0; nn < 2; ++nn)
                acc[m][nn] = __builtin_amdgcn_mfma_f32_16x16x32_bf16(aP[m], bP[nn], acc[m][nn], 0, 0, 0);
        if (it + 1 < nhalf) {
#pragma unroll
            for (int m = 0; m < 2; ++m) {
                aP[m] = *(const bf16x8*)(Ap[m] + kk + 32);
                bP[m] = *(const bf16x8*)(Bp[m] + kk + 32);
            }
        }
#pragma unroll
        for (int m = 0; m < 2; ++m)
#pragma unroll
            for (int nn = 0; nn < 2; ++nn)
                acc[m][nn] = __builtin_amdgcn_mfma_f32_16x16x32_bf16(aQ[m], bQ[nn], acc[m][nn], 0, 0, 0);
        kk += 64;
    }
#pragma unroll
    for (int m = 0; m < 2; ++m) {
#pragma unroll
        for (int nn = 0; nn < 2; ++nn) {
            int col = nbase + nn * 16 + l15;
#pragma unroll
            for (int r = 0; r < 4; ++r) {
                int row = mbase + m * 16 + lg * 4 + r;
                if (row < M) H[(size_t)row * ldH + col] = f2b(acc[m][nn][r]);
            }
        }
    }
    int hh = blockIdx.x * 2 + wcol;
    float a0 = As_[hh * 32 + l15], a1 = As_[hh * 32 + 16 + l15];
    float d0 = Ad_[hh * 32 + l15], d1 = Ad_[hh * 32 + 16 + l15];
#pragma unroll
    for (int m = 0; m < 2; ++m) {
#pragma unroll
        for (int r = 0; r < 4; ++r) {
            float ps = acc[m][0][r] * a0 + acc[m][1][r] * a1;
            float pd = acc[m][0][r] * d0 + acc[m][1][r] * d1;
            ps += __shfl_xor(ps, 1, 64); pd += __shfl_xor(pd, 1, 64);
            ps += __shfl_xor(ps, 2, 64); pd += __shfl_xor(pd, 2, 64);
            ps += __shfl_xor(ps, 4, 64); pd += __shfl_xor(pd, 4, 64);
            ps += __shfl_xor(ps, 8, 64); pd += __shfl_xor(pd, 8, 64);
            if (l15 == 0) {
                int row = mbase + m * 16 + lg * 4 + r;
                if (row < M) {
                    es[row * NN_HEADS + hh] = ps;
                    ed[row * NN_HEADS + hh] = pd;
                }
            }
        }
    }
}

// ---------------------------------------------------------------------------
// CSR build (scan + scatter)
// ---------------------------------------------------------------------------
__global__ void scan_kernel(const int* __restrict__ counts, int* __restrict__ row_start,
                            int* __restrict__ cursor, int n) {
    __shared__ int s[1024];
    int t  = threadIdx.x;
    int ch = (n + 1023) / 1024;
    int lo = t * ch;
    int sum = 0;
    for (int j = 0; j < ch; ++j) {
        int i = lo + j;
        if (i < n) sum += counts[i];
    }
    s[t] = sum;
    __syncthreads();
    for (int off = 1; off < 1024; off <<= 1) {
        int v = 0;
        if (t >= off) v = s[t - off];
        __syncthreads();
        s[t] += v;
        __syncthreads();
    }
    int run = (t == 0) ? 0 : s[t - 1];
    for (int j = 0; j < ch; ++j) {
        int i = lo + j;
        if (i < n) {
            row_start[i] = run;
            cursor[i] = run;
            run += counts[i];
        }
    }
    if (t == 1023) row_start[n] = s[1023];
}

__global__ void scatter_kernel(const int* __restrict__ src, const int* __restrict__ dst,
                               int* __restrict__ cursor, int* __restrict__ csr_src, int E) {
    int e = blockIdx.x * blockDim.x + threadIdx.x;
    if (e < E) {
        int d   = dst[e];
        int pos = atomicAdd(&cursor[d], 1);
        csr_src[pos] = src[e];
    }
}

// ---------------------------------------------------------------------------
// Hidden-layer gather, FUSED edge weights + optional rownorm; 8-deep MLP.
// ---------------------------------------------------------------------------
__global__ __launch_bounds__(256) void gather_hidden(
    const unsigned short* __restrict__ Hm, const float* __restrict__ es,
    const float* __restrict__ ed, const int* __restrict__ csr_src,
    const int* __restrict__ row_start, const unsigned short* __restrict__ last,
    unsigned short* __restrict__ out, int n, float beta,
    unsigned short* __restrict__ znb, float* __restrict__ dvec) {
    int lane = threadIdx.x & 63;
    int nn   = blockIdx.x * 4 + (threadIdx.x >> 6);
    if (nn >= n) return;
    int s0 = row_start[nn], s1 = row_start[nn + 1];
    int h2 = lane >> 3;
    float edh = ed[nn * NN_HEADS + h2];

    float zacc = 0.f;
    float a0 = 0.f, a1 = 0.f, a2 = 0.f, a3 = 0.f;
    int fullEnd = s0 + ((s1 - s0) & ~7);
    int e = s0;
    for (; e < fullEnd; e += 8) {
        int idx[8];
        float q[8];
#pragma unroll
        for (int j = 0; j < 8; ++j) idx[j] = csr_src[e + j];
#pragma unroll
        for (int j = 0; j < 8; ++j) q[j] = es[idx[j] * NN_HEADS + h2];
        ushort4 r[8];
#pragma unroll
        for (int j = 0; j < 8; ++j) r[j] = *(const ushort4*)&Hm[(size_t)idx[j] * NN_HID + lane * 4];
#pragma unroll
        for (int j = 0; j < 8; ++j) {
            float w = __expf(lrelu02(q[j] + edh));
            zacc += w;
            a0 += w * b2f(r[j].x); a1 += w * b2f(r[j].y);
            a2 += w * b2f(r[j].z); a3 += w * b2f(r[j].w);
        }
    }
    if (e < s1) {
        int c = s1 - e;
        int idx[8];
        float q[8];
#pragma unroll
        for (int j = 0; j < 8; ++j) idx[j] = csr_src[(j < c) ? e + j : e];
#pragma unroll
        for (int j = 0; j < 8; ++j) q[j] = es[idx[j] * NN_HEADS + h2];
        ushort4 r[8];
#pragma unroll
        for (int j = 0; j < 8; ++j) r[j] = *(const ushort4*)&Hm[(size_t)idx[j] * NN_HID + lane * 4];
#pragma unroll
        for (int j = 0; j < 8; ++j) {
            if (j < c) {
                float w = __expf(lrelu02(q[j] + edh));
                zacc += w;
                a0 += w * b2f(r[j].x); a1 += w * b2f(r[j].y);
                a2 += w * b2f(r[j].z); a3 += w * b2f(r[j].w);
            }
        }
    }
    float zi = 1.f / zacc;
    float v0 = elu1(a0 * zi), v1 = elu1(a1 * zi), v2 = elu1(a2 * zi), v3 = elu1(a3 * zi);
    if (beta >= 0.f) {
        ushort4 lv = *(const ushort4*)&last[(size_t)nn * NN_HID + lane * 4];
        v0 = beta * b2f(lv.x) + (1.f - beta) * v0;
        v1 = beta * b2f(lv.y) + (1.f - beta) * v1;
        v2 = beta * b2f(lv.z) + (1.f - beta) * v2;
        v3 = beta * b2f(lv.w) + (1.f - beta) * v3;
    }
    ushort4 o;
    o.x = f2b(v0); o.y = f2b(v1); o.z = f2b(v2); o.w = f2b(v3);
    *(ushort4*)&out[(size_t)nn * NN_HID + lane * 4] = o;

    if (znb) {
        float ss = v0 * v0 + v1 * v1 + v2 * v2 + v3 * v3;
        ss += __shfl_xor(ss, 1, 64);
        ss += __shfl_xor(ss, 2, 64);
        ss += __shfl_xor(ss, 4, 64);
        ss += __shfl_xor(ss, 8, 64);
        ss += __shfl_xor(ss, 16, 64);
        ss += __shfl_xor(ss, 32, 64);
        float m = fmaxf(sqrtf(ss), 1e-12f);
        float sc = ZN_SCALE / m;
        ushort4 zo;
        zo.x = f2b(v0 * sc); zo.y = f2b(v1 * sc);
        zo.z = f2b(v2 * sc); zo.w = f2b(v3 * sc);
        *(ushort4*)&znb[(size_t)nn * NN_HID + lane * 4] = zo;
        if (lane == 0) dvec[nn] = __expf((ss / (m * m)) * (1.f / TAU_F));
    }
}

// ---------------------------------------------------------------------------
// FAT KERNEL: output-layer fc (blocks [0,nfc)) + symmetric gram (rest).
// ---------------------------------------------------------------------------
__global__ __launch_bounds__(256) void gram_fc_mfma(
    const short* __restrict__ znb, float* __restrict__ P2d, int n,
    int T, int nwg, int Npad,
    const unsigned short* __restrict__ A, const unsigned short* __restrict__ Bw,
    unsigned short* __restrict__ H, int M, int nfc, int fcX) {
    __shared__ short As[2][128 * 64];
    __shared__ short Bs[2][128 * 64];

    int t    = threadIdx.x;
    int lane = t & 63;
    int wid  = t >> 6;
    int l15  = lane & 15, lg = lane >> 4;

    if (blockIdx.x < nfc) {
        const int K = 256, ncols = 320, ldH = 320;
        int idx = blockIdx.x;
        int bx = idx % fcX, by = idx / fcX;
        int wrow = wid >> 1, wcol = wid & 1;
        int mbase = by * 64 + wrow * 32;
        int nbase = bx * 64 + wcol * 32;

        const unsigned short* Ap[2];
        const unsigned short* Bp[2];
#pragma unroll
        for (int m = 0; m < 2; ++m) {
            int rr = mbase + m * 16 + l15;
            if (rr > M - 1) rr = M - 1;
            Ap[m] = A + (size_t)rr * K + lg * 8;
            Bp[m] = Bw + (size_t)(nbase + m * 16 + l15) * K + lg * 8;
        }
        f32x4 acc[2][2];
#pragma unroll
        for (int m = 0; m < 2; ++m)
#pragma unroll
            for (int nn = 0; nn < 2; ++nn)
#pragma unroll
                for (int r = 0; r < 4; ++r) acc[m][nn][r] = 0.f;

        bf16x8 aP[2], bP[2], aQ[2], bQ[2];
#pragma unroll
        for (int m = 0; m < 2; ++m) {
            aP[m] = *(const bf16x8*)(Ap[m]);
            bP[m] = *(const bf16x8*)(Bp[m]);
        }
        int kk = 32;
#pragma unroll
        for (int it = 0; it < 4; ++it) {
#pragma unroll
            for (int m = 0; m < 2; ++m) {
                aQ[m] = *(const bf16x8*)(Ap[m] + kk);
                bQ[m] = *(const bf16x8*)(Bp[m] + kk);
            }
#pragma unroll
            for (int m = 0; m < 2; ++m)
#pragma unroll
                for (int nn = 0; nn < 2; ++nn)
                    acc[m][nn] = __builtin_amdgcn_mfma_f32_16x16x32_bf16(aP[m], bP[nn], acc[m][nn], 0, 0, 0);
            if (it < 3) {
#pragma unroll
                for (int m = 0; m < 2; ++m) {
                    aP[m] = *(const bf16x8*)(Ap[m] + kk + 32);
                    bP[m] = *(const bf16x8*)(Bp[m] + kk + 32);
                }
            }
#pragma unroll
            for (int m = 0; m < 2; ++m)
#pragma unroll
                for (int nn = 0; nn < 2; ++nn)
                    acc[m][nn] = __builtin_amdgcn_mfma_f32_16x16x32_bf16(aQ[m], bQ[nn], acc[m][nn], 0, 0, 0);
            kk += 64;
        }
#pragma unroll
        for (int m = 0; m < 2; ++m) {
#pragma unroll
            for (int nn = 0; nn < 2; ++nn) {
                int col = nbase + nn * 16 + l15;
                if (col >= ncols) continue;
#pragma unroll
                for (int r = 0; r < 4; ++r) {
                    int row = mbase + m * 16 + lg * 4 + r;
                    if (row < M) H[(size_t)row * ldH + col] = f2b(acc[m][nn][r]);
                }
            }
        }
        return;
    }

    // gram path
    int b = blockIdx.x - nfc;
    int q = nwg >> 3, r8 = nwg & 7, xc = b & 7, oo = b >> 3;
    int sid = (xc < r8 ? xc * (q + 1) : r8 * (q + 1) + (xc - r8) * q) + oo;
    int bi = 0, rem = sid;
    while (rem >= T - bi) { rem -= T - bi; ++bi; }
    int bj = bi + rem;
    int i0 = bi * 128, j0 = bj * 128;

    int wrow = wid >> 1, wcol = wid & 1;
    int srow = lane >> 3;
    int sch  = lane & 7;

    f32x4 acc[4][4];
#pragma unroll
    for (int m = 0; m < 4; ++m)
#pragma unroll
        for (int nn = 0; nn < 4; ++nn)
#pragma unroll
            for (int r = 0; r < 4; ++r) acc[m][nn][r] = 0.f;

    bf16x8 sa[2][4], sb[2][4];
#pragma unroll
    for (int sl = 0; sl < 2; ++sl)
#pragma unroll
        for (int s = 0; s < 4; ++s) {
            int row = wid * 32 + s * 8 + srow;
            int gch = sch ^ (row & 7);
            sa[sl][s] = *(const bf16x8*)(znb + (size_t)(i0 + row) * NN_HID + sl * 64 + gch * 8);
            sb[sl][s] = *(const bf16x8*)(znb + (size_t)(j0 + row) * NN_HID + sl * 64 + gch * 8);
        }

#pragma unroll
    for (int kt = 0; kt < 2; ++kt) {
#pragma unroll
        for (int sl = 0; sl < 2; ++sl)
#pragma unroll
            for (int s = 0; s < 4; ++s) {
                int row = wid * 32 + s * 8 + srow;
                *(bf16x8*)(&As[sl][row * 64 + sch * 8]) = sa[sl][s];
                *(bf16x8*)(&Bs[sl][row * 64 + sch * 8]) = sb[sl][s];
            }
        __syncthreads();
        if (kt == 0) {
#pragma unroll
            for (int sl = 0; sl < 2; ++sl)
#pragma unroll
                for (int s = 0; s < 4; ++s) {
                    int row = wid * 32 + s * 8 + srow;
                    int gch = sch ^ (row & 7);
                    sa[sl][s] = *(const bf16x8*)(znb + (size_t)(i0 + row) * NN_HID + 128 + sl * 64 + gch * 8);
                    sb[sl][s] = *(const bf16x8*)(znb + (size_t)(j0 + row) * NN_HID + 128 + sl * 64 + gch * 8);
                }
        }
#pragma unroll
        for (int sl = 0; sl < 2; ++sl) {
#pragma unroll
            for (int ks = 0; ks < 2; ++ks) {
                bf16x8 av[4], bv[4];
#pragma unroll
                for (int m = 0; m < 4; ++m) {
                    int Ra = wrow * 64 + m * 16 + l15;
                    int Rb = wcol * 64 + m * 16 + l15;
                    int ca = (ks * 4 + lg) ^ (Ra & 7);
                    int cb = (ks * 4 + lg) ^ (Rb & 7);
                    av[m] = *(const bf16x8*)(&As[sl][Ra * 64 + ca * 8]);
                    bv[m] = *(const bf16x8*)(&Bs[sl][Rb * 64 + cb * 8]);
                }
#pragma unroll
                for (int m = 0; m < 4; ++m)
#pragma unroll
                    for (int nn = 0; nn < 4; ++nn)
                        acc[m][nn] = __builtin_amdgcn_mfma_f32_16x16x32_bf16(av[m], bv[nn], acc[m][nn], 0, 0, 0);
            }
        }
        if (kt == 0) __syncthreads();
    }

    int i0w = i0 + wrow * 64;
    int j0w = j0 + wcol * 64;
    bool diag = (bj == bi);
    if (bj == T - 1) {
#pragma unroll
        for (int m = 0; m < 4; ++m)
#pragma unroll
            for (int nn = 0; nn < 4; ++nn) {
                int gj = j0w + nn * 16 + l15;
                bool jok = gj < n;
#pragma unroll
                for (int r = 0; r < 4; ++r) {
                    int gi = i0w + m * 16 + lg * 4 + r;
                    acc[m][nn][r] = (jok && gi < n) ? __builtin_exp2f(acc[m][nn][r]) : 0.f;
                }
            }
    } else {
#pragma unroll
        for (int m = 0; m < 4; ++m)
#pragma unroll
            for (int nn = 0; nn < 4; ++nn)
#pragma unroll
                for (int r = 0; r < 4; ++r)
                    acc[m][nn][r] = __builtin_exp2f(acc[m][nn][r]);
    }
    float* rowslot = P2d + (size_t)(2 * bj + wcol) * Npad;
#pragma unroll
    for (int m = 0; m < 4; ++m) {
#pragma unroll
        for (int r = 0; r < 4; ++r) {
            float v = acc[m][0][r] + acc[m][1][r] + acc[m][2][r] + acc[m][3][r];
            v += __shfl_xor(v, 1, 64);
            v += __shfl_xor(v, 2, 64);
            v += __shfl_xor(v, 4, 64);
            v += __shfl_xor(v, 8, 64);
            if (l15 == 0) {
                int gi = i0w + m * 16 + lg * 4 + r;
                if (gi < n) rowslot[gi] = v;
            }
        }
    }
    if (!diag) {
        float* colslot = P2d + (size_t)(2 * bi + wrow) * Npad;
#pragma unroll
        for (int nn = 0; nn < 4; ++nn) {
            float v = 0.f;
#pragma unroll
            for (int m = 0; m < 4; ++m)
#pragma unroll
                for (int r = 0; r < 4; ++r) v += acc[m][nn][r];
            v += __shfl_xor(v, 16, 64);
            v += __shfl_xor(v, 32, 64);
            if (lg == 0) {
                int gj = j0w + nn * 16 + l15;
                if (gj < n) colslot[gj] = v;
            }
        }
    }
}

// ---------------------------------------------------------------------------
// FAT: final-layer attn dots (blocks [0,nAt)) + fold (rest). Independent.
// ---------------------------------------------------------------------------
__global__ __launch_bounds__(256) void attn_fold_kernel(
    const unsigned short* __restrict__ Hm, const float* __restrict__ As,
    const float* __restrict__ Ad, float* __restrict__ es, float* __restrict__ ed,
    int n, int df, int nAt,
    const float* __restrict__ P2d, float* __restrict__ R, int slots, int Npad) {
    if (blockIdx.x < nAt) {
        int idx = blockIdx.x * 256 + threadIdx.x;
        if (idx >= n * NN_HEADS) return;
        int nn = idx / NN_HEADS, hh = idx - nn * NN_HEADS;
        const unsigned short* hp = Hm + (size_t)nn * NN_HEADS * df + hh * df;
        const float* ap = As + hh * df;
        const float* bp = Ad + hh * df;
        float s1 = 0.f, s2 = 0.f;
        for (int d = 0; d < df; d += 4) {
            ushort4 hv = *(const ushort4*)(hp + d);
            float4 av = *(const float4*)(ap + d);
            float4 bv = *(const float4*)(bp + d);
            float h0 = b2f(hv.x), h1 = b2f(hv.y), h2 = b2f(hv.z), h3 = b2f(hv.w);
            s1 += h0 * av.x + h1 * av.y + h2 * av.z + h3 * av.w;
            s2 += h0 * bv.x + h1 * bv.y + h2 * bv.z + h3 * bv.w;
        }
        es[idx] = s1;
        ed[idx] = s2;
        return;
    }
    int i = (blockIdx.x - nAt) * 256 + threadIdx.x;
    if (i >= n) return;
    const float* p = P2d + i;
    float s0 = 0.f, s1 = 0.f, s2 = 0.f, s3 = 0.f;
    int sl = 0;
    for (; sl + 4 <= slots; sl += 4) {
        s0 += p[(size_t)(sl + 0) * Npad];
        s1 += p[(size_t)(sl + 1) * Npad];
        s2 += p[(size_t)(sl + 2) * Npad];
        s3 += p[(size_t)(sl + 3) * Npad];
    }
    for (; sl < slots; ++sl) s0 += p[(size_t)sl * Npad];
    R[i] = (s0 + s1) + (s2 + s3);
}

// ---------------------------------------------------------------------------
// FAT: edge weights (blocks [0,nEw)) + loss reduction (last block).
// ---------------------------------------------------------------------------
__global__ __launch_bounds__(256) void edge_loss_kernel(
    const float* __restrict__ es, const float* __restrict__ ed,
    const int* __restrict__ csr_src, const int* __restrict__ row_start,
    float* __restrict__ wC, float* __restrict__ zinv, int n, int nEw,
    const float* __restrict__ R, const float* __restrict__ dvec,
    float* __restrict__ out_loss) {
    if (blockIdx.x < nEw) {
        int lane = threadIdx.x & 63;
        int nn   = blockIdx.x * 4 + (threadIdx.x >> 6);
        if (nn >= n) return;
        int s0 = row_start[nn], s1 = row_start[nn + 1];
        int h    = lane & 7;
        int slot = lane >> 3;
        float edh = ed[nn * NN_HEADS + h];
        float z = 0.f;
        for (int e = s0 + slot; e < s1; e += 8) {
            int sv = csr_src[e];
            float w = __expf(lrelu02(es[sv * NN_HEADS + h] + edh));
            wC[(size_t)e * NN_HEADS + h] = w;
            z += w;
        }
        z += __shfl_xor(z, 8, 64);
        z += __shfl_xor(z, 16, 64);
        z += __shfl_xor(z, 32, 64);
        if (slot == 0) zinv[nn * NN_HEADS + h] = 1.f / z;
        return;
    }
    // loss block (256 threads)
    __shared__ float s[256];
    int t = threadIdx.x;
    float sum = 0.f;
    for (int i = t; i < n; i += 256) {
        float d   = dvec[i];
        float off = R[i] - d;
        sum += -logf(d / (off + off));
    }
    s[t] = sum;
    __syncthreads();
    for (int o = 128; o > 0; o >>= 1) {
        if (t < o) s[t] += s[t + o];
        __syncthreads();
    }
    if (t == 0) *out_loss = s[0] / n;
}

// ---------------------------------------------------------------------------
// Final layer gather: weighted sum + head-mean + log_softmax; 8-deep MLP.
// ---------------------------------------------------------------------------
__global__ void gather_final(const unsigned short* __restrict__ Hm, const float* __restrict__ wC,
                             const float* __restrict__ zinv, const int* __restrict__ csr_src,
                             const int* __restrict__ row_start, float* __restrict__ dout, int n) {
    int nn = blockIdx.x;
    __shared__ float accs[NN_HEADS * NN_NCLASS];
    int t = threadIdx.x;  // 0..319
    int s0 = row_start[nn], s1 = row_start[nn + 1];
    int hh = t / NN_NCLASS;
    float acc = 0.f;
    const int LD = NN_HEADS * NN_NCLASS;
    int fullEnd = s0 + ((s1 - s0) & ~7);
    int e = s0;
    for (; e < fullEnd; e += 8) {
        int idx[8];
        float wv[8];
#pragma unroll
        for (int j = 0; j < 8; ++j) {
            idx[j] = csr_src[e + j];
            wv[j]  = wC[(size_t)(e + j) * NN_HEADS + hh];
        }
        float v[8];
#pragma unroll
        for (int j = 0; j < 8; ++j) v[j] = b2f(Hm[(size_t)idx[j] * LD + t]);
#pragma unroll
        for (int j = 0; j < 8; ++j) acc += wv[j] * v[j];
    }
    if (e < s1) {
        int c = s1 - e;
        int idx[8];
        float wv[8];
#pragma unroll
        for (int j = 0; j < 8; ++j) {
            int p = (j < c) ? e + j : e;
            idx[j] = csr_src[p];
            wv[j]  = wC[(size_t)p * NN_HEADS + hh];
        }
        float v[8];
#pragma unroll
        for (int j = 0; j < 8; ++j) v[j] = b2f(Hm[(size_t)idx[j] * LD + t]);
#pragma unroll
        for (int j = 0; j < 8; ++j) {
            if (j < c) acc += wv[j] * v[j];
        }
    }
    accs[t] = acc * zinv[nn * NN_HEADS + hh];
    __syncthreads();
    if (t < 64) {
        float v = -INFINITY;
        if (t < NN_NCLASS) {
            float sacc = 0.f;
#pragma unroll
            for (int h2 = 0; h2 < NN_HEADS; ++h2) sacc += accs[h2 * NN_NCLASS + t];
            v = sacc * (1.f / NN_HEADS);
        }
        float mx = v;
#pragma unroll
        for (int o = 1; o < 64; o <<= 1) mx = fmaxf(mx, __shfl_xor(mx, o, 64));
        float ex = (t < NN_NCLASS) ? expf(v - mx) : 0.f;
        float se = ex;
#pragma unroll
        for (int o = 1; o < 64; o <<= 1) se += __shfl_xor(se, o, 64);
        if (t < NN_NCLASS) dout[(size_t)nn * NN_NCLASS + t] = (v - mx) - logf(se);
    }
}

// ---------------------------------------------------------------------------
extern "C" void kernel_launch(void* const* d_in, const int* in_sizes, int n_in,
                              void* d_out, int out_size, void* d_ws, size_t ws_size,
                              hipStream_t stream) {
    const float* x   = (const float*)d_in[0];
    const int*   src = (const int*)d_in[1];
    const int*   dst = (const int*)d_in[2];
    const float* W0  = (const float*)d_in[3];
    const float* a0s = (const float*)d_in[4];
    const float* a0d = (const float*)d_in[5];
    const float* W1  = (const float*)d_in[6];
    const float* a1s = (const float*)d_in[7];
    const float* a1d = (const float*)d_in[8];
    const float* W2  = (const float*)d_in[9];
    const float* a2s = (const float*)d_in[10];
    const float* a2d = (const float*)d_in[11];
    const float* Wout= (const float*)d_in[12];
    const float* aos = (const float*)d_in[13];
    const float* aod = (const float*)d_in[14];

    int N = in_sizes[0] / NN_F_IN;
    int E = in_sizes[1];
    int Npad = ((N + 127) / 128) * 128;
    int T = Npad / 128;
    int nwg = T * (T + 1) / 2;
    float* out = (float*)d_out;

    char*  ws  = (char*)d_ws;
    size_t off = 0;
    auto alloc = [&](size_t bytes) -> void* {
        void* p = ws + off;
        off += bytes;
        off = (off + 255) & ~(size_t)255;
        return p;
    };
    unsigned short* Hb = (unsigned short*)alloc((size_t)N * 320 * 2);
    unsigned short* znb = (unsigned short*)alloc((size_t)Npad * NN_HID * 2);
    unsigned short* Bl = (unsigned short*)alloc((size_t)N * NN_HID * 2);
    unsigned short* Bc = (unsigned short*)alloc((size_t)N * NN_HID * 2);
    size_t xbBytes = (size_t)N * NN_F_IN * 2;
    size_t p2Bytes = (size_t)2 * T * Npad * 4;
    void* XbP2d = alloc(xbBytes > p2Bytes ? xbBytes : p2Bytes);
    unsigned short* Xb  = (unsigned short*)XbP2d;
    float*          P2d = (float*)XbP2d;
    unsigned short* Wt0 = (unsigned short*)alloc((size_t)256 * 512 * 2);
    unsigned short* Wt1 = (unsigned short*)alloc((size_t)256 * 256 * 2);
    unsigned short* Wt2 = (unsigned short*)alloc((size_t)256 * 256 * 2);
    unsigned short* Wto = (unsigned short*)alloc((size_t)384 * 256 * 2);
    float* es     = (float*)alloc((size_t)N * NN_HEADS * 4);
    float* ed     = (float*)alloc((size_t)N * NN_HEADS * 4);
    float* wC     = (float*)alloc((size_t)E * NN_HEADS * 4);
    float* zinvA  = (float*)alloc((size_t)N * NN_HEADS * 4);
    float* Rrow   = (float*)alloc((size_t)N * 4);
    float* dvec   = (float*)alloc((size_t)N * 4);
    int*   counts = (int*)alloc((size_t)N * 4);
    int*   rs     = (int*)alloc((size_t)(N + 1) * 4);
    int*   cursor = (int*)alloc((size_t)N * 4);
    int*   csr    = (int*)alloc((size_t)E * 4);

    // ---- memsets (counts + znb pad rows)
    hipMemsetAsync(counts, 0, (size_t)N * 4, stream);
    if (Npad > N)
        hipMemsetAsync(znb + (size_t)N * NN_HID, 0, (size_t)(Npad - N) * NN_HID * 2, stream);

    // ---- FAT front: count + prep
    int n4X = N * NN_F_IN / 4;
    int prepTotal = n4X + 256 * 512 + 256 * 256 + 256 * 256 + 384 * 256;
    int nCountB = (E + 255) / 256;
    int nPrepB  = (prepTotal + 255) / 256;
    prep_count_kernel<<<nCountB + nPrepB, 256, 0, stream>>>(
        x, W0, W1, W2, Wout, Xb, Wt0, Wt1, Wt2, Wto, n4X, dst, counts, E, nCountB);
    scan_kernel<<<1, 1024, 0, stream>>>(counts, rs, cursor, N);
    scatter_kernel<<<(E + 255) / 256, 256, 0, stream>>>(src, dst, cursor, csr, E);

    int atGrid = (N * NN_HEADS + 255) / 256;
    int ghGrid = (N + 3) / 4;
    int mT64 = (N + 63) / 64;

    // ---- layer 0: Xb -> Hb (+es/ed fused) -> Bl
    fc_attn_mfma<<<dim3(4, mT64), 256, 0, stream>>>(Xb, Wt0, Hb, a0s, a0d, es, ed, N, 512);
    gather_hidden<<<ghGrid, 256, 0, stream>>>(Hb, es, ed, csr, rs, nullptr, Bl, N, -1.f,
                                              nullptr, nullptr);

    // ---- layer 1: Bl -> Hb (+es/ed) -> Bc (beta = 0.5/3)
    fc_attn_mfma<<<dim3(4, mT64), 256, 0, stream>>>(Bl, Wt1, Hb, a1s, a1d, es, ed, N, 256);
    gather_hidden<<<ghGrid, 256, 0, stream>>>(Hb, es, ed, csr, rs, Bl, Bc, N, LAMDA_F / 3.f,
                                              nullptr, nullptr);

    // ---- layer 2: Bc -> Hb (+es/ed) -> Bl (beta = 0.5/4) + FUSED rownorm
    fc_attn_mfma<<<dim3(4, mT64), 256, 0, stream>>>(Bc, Wt2, Hb, a2s, a2d, es, ed, N, 256);
    gather_hidden<<<ghGrid, 256, 0, stream>>>(Hb, es, ed, csr, rs, Bc, Bl, N, LAMDA_F / 4.f,
                                              znb, dvec);

    // ---- FAT: output-layer fc (Bl->Hb, 320 cols) + gram (znb->P2d)
    int fcX = 5;
    int nfc = fcX * mT64;
    gram_fc_mfma<<<nfc + nwg, 256, 0, stream>>>((const short*)znb, P2d, N, T, nwg, Npad,
                                                Bl, Wto, Hb, N, nfc, fcX);

    // ---- FAT: attn(final) + fold   (both depend only on fat kernel)
    int foldB = (N + 255) / 256;
    attn_fold_kernel<<<atGrid + foldB, 256, 0, stream>>>(
        Hb, aos, aod, es, ed, N, NN_NCLASS, atGrid, P2d, Rrow, 2 * T, Npad);

    // ---- FAT: edge_wz + loss
    edge_loss_kernel<<<ghGrid + 1, 256, 0, stream>>>(
        es, ed, csr, rs, wC, zinvA, N, ghGrid, Rrow, dvec,
        out + (size_t)N * NN_NCLASS);

    // ---- final gather -> d_out
    gather_final<<<N, NN_HEADS * NN_NCLASS, 0, stream>>>(Hb, wC, zinvA, csr, rs, out, N);
}